// Round 1
// baseline (2991.261 us; speedup 1.0000x reference)
//
#include <hip/hip_runtime.h>
#include <math.h>

namespace {
constexpr int B = 4, S = 2048, E = 512, D = 64, H = 8;

// Q/K/Vd projections: per (b,h), [S,E] @ [E,D] -> [S,D] for three weights.
// Block: 256 threads = 4 waves; wave sg handles 16 consecutive rows; lane d = out col.
__global__ __launch_bounds__(256) void proj_kernel(
    const float* __restrict__ x, const float* __restrict__ Wq,
    const float* __restrict__ Wk, const float* __restrict__ Wvd,
    float* __restrict__ Q, float* __restrict__ K, float* __restrict__ Vd) {
  const int bh = blockIdx.x;          // 0..B*H-1
  const int b = bh / H, h = bh % H;
  const int s0 = blockIdx.y * 64;
  const int d = threadIdx.x & 63;
  const int sg = threadIdx.x >> 6;    // 0..3
  const int srow = s0 + sg * 16;
  float aq[16] = {}, ak[16] = {}, av[16] = {};
  const float* xbase = x + (size_t)(b * S + srow) * E;
  const float* wqb = Wq + (size_t)h * E * D + d;
  const float* wkb = Wk + (size_t)h * E * D + d;
  const float* wvb = Wvd + (size_t)h * E * D + d;
  for (int e = 0; e < E; ++e) {
    const float wq = wqb[(size_t)e * D];
    const float wk = wkb[(size_t)e * D];
    const float wv = wvb[(size_t)e * D];
#pragma unroll
    for (int r = 0; r < 16; ++r) {
      const float xv = xbase[(size_t)r * E + e];
      aq[r] = fmaf(xv, wq, aq[r]);
      ak[r] = fmaf(xv, wk, ak[r]);
      av[r] = fmaf(xv, wv, av[r]);
    }
  }
  const size_t obase = ((size_t)bh * S + srow) * D + d;
#pragma unroll
  for (int r = 0; r < 16; ++r) {
    Q[obase + (size_t)r * D] = aq[r];
    K[obase + (size_t)r * D] = ak[r];
    Vd[obase + (size_t)r * D] = av[r];
  }
}

// W2[(h*D+d), e] = Wvu[h,d,e] * Wo[h]  (folds head-combine weight into value-up)
__global__ __launch_bounds__(256) void w2_kernel(
    const float* __restrict__ Wvu, const float* __restrict__ Wo,
    float* __restrict__ W2) {
  const int idx = blockIdx.x * 256 + threadIdx.x;  // over H*D*E
  const int h = idx / (D * E);
  W2[idx] = Wvu[idx] * Wo[h];
}

// Online-softmax causal attention, one thread per query row.
// Replicates reference masking: upper triangle AND exact-zero scores -> -inf.
__global__ __launch_bounds__(256) void attn_kernel(
    const float* __restrict__ Q, const float* __restrict__ K,
    const float* __restrict__ Vd, float* __restrict__ PVd) {
  const int bh = blockIdx.x;
  const int s = blockIdx.y * 256 + threadIdx.x;
  const int b = bh / H, h = bh % H;
  const float4* qp = (const float4*)(Q + ((size_t)bh * S + s) * D);
  float4 q[16];
#pragma unroll
  for (int i = 0; i < 16; ++i) q[i] = qp[i];
  // fold 1/sqrt(D)=0.125 into q: exact (power of two), preserves zero-set
#pragma unroll
  for (int i = 0; i < 16; ++i) {
    q[i].x *= 0.125f; q[i].y *= 0.125f; q[i].z *= 0.125f; q[i].w *= 0.125f;
  }
  float m = -INFINITY, l = 0.f;
  float4 acc[16] = {};
  const float4* Kb = (const float4*)(K + (size_t)bh * S * D);
  const float4* Vb = (const float4*)(Vd + (size_t)bh * S * D);
  for (int t = 0; t <= s; ++t) {
    const float4* kp = Kb + (size_t)t * 16;
    float sc = 0.f;
#pragma unroll
    for (int i = 0; i < 16; ++i) {
      const float4 kv = kp[i];
      sc = fmaf(q[i].x, kv.x, sc);
      sc = fmaf(q[i].y, kv.y, sc);
      sc = fmaf(q[i].z, kv.z, sc);
      sc = fmaf(q[i].w, kv.w, sc);
    }
    if (sc != 0.f) {  // reference maps exact-zero scores to -inf (excluded)
      float p;
      if (sc > m) {
        const float r = __expf(m - sc);  // m=-inf first time -> r=0
        l *= r;
#pragma unroll
        for (int i = 0; i < 16; ++i) {
          acc[i].x *= r; acc[i].y *= r; acc[i].z *= r; acc[i].w *= r;
        }
        m = sc;
        p = 1.f;
      } else {
        p = __expf(sc - m);
      }
      l += p;
      const float4* vp = Vb + (size_t)t * 16;
#pragma unroll
      for (int i = 0; i < 16; ++i) {
        const float4 vv = vp[i];
        acc[i].x = fmaf(p, vv.x, acc[i].x);
        acc[i].y = fmaf(p, vv.y, acc[i].y);
        acc[i].z = fmaf(p, vv.z, acc[i].z);
        acc[i].w = fmaf(p, vv.w, acc[i].w);
      }
    }
  }
  const float inv = 1.f / l;
  // PVd layout [B,S,H,D] so the final GEMM sees [B*S, H*D] contiguous
  float4* op = (float4*)(PVd + (((size_t)b * S + s) * H + h) * D);
#pragma unroll
  for (int i = 0; i < 16; ++i) {
    float4 o = acc[i];
    o.x *= inv; o.y *= inv; o.z *= inv; o.w *= inv;
    op[i] = o;
  }
}

// out[B*S, E] = PVd[B*S, H*D] @ W2[H*D, E]
__global__ __launch_bounds__(256) void out_kernel(
    const float* __restrict__ A, const float* __restrict__ W2,
    float* __restrict__ out) {
  const int row0 = blockIdx.x * 16;
  const int e = blockIdx.y * 256 + threadIdx.x;
  float acc[16] = {};
  const float* Ab = A + (size_t)row0 * (H * D);
  for (int k = 0; k < H * D; ++k) {
    const float w = W2[(size_t)k * E + e];
#pragma unroll
    for (int r = 0; r < 16; ++r)
      acc[r] = fmaf(Ab[(size_t)r * (H * D) + k], w, acc[r]);
  }
#pragma unroll
  for (int r = 0; r < 16; ++r) out[(size_t)(row0 + r) * E + e] = acc[r];
}

}  // namespace

extern "C" void kernel_launch(void* const* d_in, const int* in_sizes, int n_in,
                              void* d_out, int out_size, void* d_ws, size_t ws_size,
                              hipStream_t stream) {
  const float* x   = (const float*)d_in[0];
  const float* Wq  = (const float*)d_in[1];
  const float* Wk  = (const float*)d_in[2];
  const float* Wvd = (const float*)d_in[3];
  const float* Wvu = (const float*)d_in[4];
  const float* Wo  = (const float*)d_in[5];
  float* out = (float*)d_out;

  const size_t nqk = (size_t)B * H * S * D;  // 4.19M floats each
  float* Q   = (float*)d_ws;
  float* K   = Q + nqk;
  float* Vd  = K + nqk;
  float* PVd = Vd + nqk;
  float* W2  = PVd + nqk;  // H*D*E floats

  proj_kernel<<<dim3(B * H, S / 64), 256, 0, stream>>>(x, Wq, Wk, Wvd, Q, K, Vd);
  w2_kernel<<<dim3(H * D * E / 256), 256, 0, stream>>>(Wvu, Wo, W2);
  attn_kernel<<<dim3(B * H, S / 256), 256, 0, stream>>>(Q, K, Vd, PVd);
  out_kernel<<<dim3(B * S / 16, E / 256), 256, 0, stream>>>(PVd, W2, out);
}

// Round 2
// 727.622 us; speedup vs baseline: 4.1110x; 4.1110x over previous
//
#include <hip/hip_runtime.h>
#include <math.h>

namespace {
constexpr int B = 4, S = 2048, E = 512, D = 64, H = 8;

// ---------------------------------------------------------------------------
// proj: for each (b,h,w): [S,E] @ [E,D] -> Q/K/Vd.  Treated as one big GEMM
// x[B*S, E] @ W_all[E, 3*H*D]; a 64-wide column block == exactly one (w,h).
// 64x64 C-tile, 4x4 micro-tile per thread, LDS-staged chunks of k=64.
// ---------------------------------------------------------------------------
__global__ __launch_bounds__(256) void proj_kernel(
    const float* __restrict__ x, const float* __restrict__ Wq,
    const float* __restrict__ Wk, const float* __restrict__ Wvd,
    float* __restrict__ Q, float* __restrict__ K, float* __restrict__ Vd) {
  const int rb = blockIdx.x;            // row block over B*S (128 blocks)
  const int cb = blockIdx.y;            // 0..23 -> (w, h)
  const int w = cb >> 3, h = cb & 7;
  const float* Wsel = (w == 0) ? Wq : (w == 1) ? Wk : Wvd;
  const float* Wp = Wsel + (size_t)h * E * D;       // [E][D]
  float* Out = (w == 0) ? Q : (w == 1) ? K : Vd;

  __shared__ float As[64][68];  // As[r][k]
  __shared__ float Bs[64][68];  // Bs[k][d]
  const int tid = threadIdx.x;
  const int tx = tid & 15, ty = tid >> 4;  // col4, row4
  const int row0 = rb * 64;

  float acc[4][4] = {};
  for (int k0 = 0; k0 < E; k0 += 64) {
    __syncthreads();
#pragma unroll
    for (int j = 0; j < 4; ++j) {
      const int flat = tid + j * 256;          // 0..1023 float4 slots
      const int r = flat >> 4, c4 = flat & 15;
      *(float4*)&As[r][c4 * 4] =
          *(const float4*)(x + (size_t)(row0 + r) * E + k0 + c4 * 4);
      *(float4*)&Bs[r][c4 * 4] =
          *(const float4*)(Wp + (size_t)(k0 + r) * D + c4 * 4);
    }
    __syncthreads();
#pragma unroll 8
    for (int k = 0; k < 64; ++k) {
      float a0 = As[ty * 4 + 0][k], a1 = As[ty * 4 + 1][k];
      float a2 = As[ty * 4 + 2][k], a3 = As[ty * 4 + 3][k];
      float4 bv = *(const float4*)&Bs[k][tx * 4];
      acc[0][0] = fmaf(a0, bv.x, acc[0][0]); acc[0][1] = fmaf(a0, bv.y, acc[0][1]);
      acc[0][2] = fmaf(a0, bv.z, acc[0][2]); acc[0][3] = fmaf(a0, bv.w, acc[0][3]);
      acc[1][0] = fmaf(a1, bv.x, acc[1][0]); acc[1][1] = fmaf(a1, bv.y, acc[1][1]);
      acc[1][2] = fmaf(a1, bv.z, acc[1][2]); acc[1][3] = fmaf(a1, bv.w, acc[1][3]);
      acc[2][0] = fmaf(a2, bv.x, acc[2][0]); acc[2][1] = fmaf(a2, bv.y, acc[2][1]);
      acc[2][2] = fmaf(a2, bv.z, acc[2][2]); acc[2][3] = fmaf(a2, bv.w, acc[2][3]);
      acc[3][0] = fmaf(a3, bv.x, acc[3][0]); acc[3][1] = fmaf(a3, bv.y, acc[3][1]);
      acc[3][2] = fmaf(a3, bv.z, acc[3][2]); acc[3][3] = fmaf(a3, bv.w, acc[3][3]);
    }
  }
  // write: layout [(b*H+h)*S + s][d]
#pragma unroll
  for (int i = 0; i < 4; ++i) {
    const int row = row0 + ty * 4 + i;
    const int b = row >> 11, s = row & (S - 1);
    float4 v = make_float4(acc[i][0], acc[i][1], acc[i][2], acc[i][3]);
    *(float4*)(Out + (((size_t)(b * H + h) * S + s) * D) + tx * 4) = v;
  }
}

// W2[(h*D+d), e] = Wvu[h,d,e] * Wo[h]
__global__ __launch_bounds__(256) void w2_kernel(
    const float* __restrict__ Wvu, const float* __restrict__ Wo,
    float* __restrict__ W2) {
  const int idx = blockIdx.x * 256 + threadIdx.x;
  const int h = idx >> 15;  // / (D*E)
  W2[idx] = Wvu[idx] * Wo[h];
}

// ---------------------------------------------------------------------------
// attn: flash-style, fp32. Block = (bh, 64 q rows). Thread (tq=tid>>2, g=tid&3)
// owns q-row tq's scores for t in [g*16,g*16+16) and output dims [g*16,g*16+16).
// K staged XOR-swizzled in LDS (kills 4-way conflict), V linear, P via
// wave-private LDS rows (no barrier needed).
// Masking replicates reference: (t<=s) && (score != 0), else -inf.
// ---------------------------------------------------------------------------
__global__ __launch_bounds__(256) void attn_kernel(
    const float* __restrict__ Q, const float* __restrict__ K,
    const float* __restrict__ Vd, float* __restrict__ PVd) {
  const int bh = blockIdx.x, qt = blockIdx.y;
  const int b = bh >> 3, h = bh & 7;
  const int tid = threadIdx.x;
  const int tq = tid >> 2, g = tid & 3;
  const int s = qt * 64 + tq;

  __shared__ float Ks[64][68];  // swizzled: slot c4 stored at c4^(t>>4)
  __shared__ float Vs[64][68];
  __shared__ float Ps[64][65];

  float4 q[16];
  {
    const float4* qp = (const float4*)(Q + ((size_t)bh * S + s) * D);
#pragma unroll
    for (int i = 0; i < 16; ++i) {
      q[i] = qp[i];
      q[i].x *= 0.125f; q[i].y *= 0.125f; q[i].z *= 0.125f; q[i].w *= 0.125f;
    }
  }
  float m = -INFINITY, l = 0.f;
  float acc[16] = {};
  const float* Kg = K + (size_t)bh * S * D;
  const float* Vg = Vd + (size_t)bh * S * D;

  for (int kt = 0; kt <= qt; ++kt) {
    __syncthreads();
#pragma unroll
    for (int j = 0; j < 4; ++j) {
      const int flat = tid + j * 256;
      const int t = flat >> 4, c4 = flat & 15;
      const size_t gaddr = (size_t)(kt * 64 + t) * D + c4 * 4;
      *(float4*)&Ks[t][((c4 ^ (t >> 4)) << 2)] = *(const float4*)(Kg + gaddr);
      *(float4*)&Vs[t][c4 << 2] = *(const float4*)(Vg + gaddr);
    }
    __syncthreads();

    float sc[16];
#pragma unroll 4
    for (int t2 = 0; t2 < 16; ++t2) {
      const int t = (g << 4) + t2;
      float s0 = 0.f, s1 = 0.f, s2 = 0.f, s3 = 0.f;
#pragma unroll
      for (int k4 = 0; k4 < 16; k4 += 4) {
        float4 k0 = *(const float4*)&Ks[t][((k4 + 0) ^ g) << 2];
        float4 k1 = *(const float4*)&Ks[t][((k4 + 1) ^ g) << 2];
        float4 k2 = *(const float4*)&Ks[t][((k4 + 2) ^ g) << 2];
        float4 k3 = *(const float4*)&Ks[t][((k4 + 3) ^ g) << 2];
        s0 = fmaf(q[k4+0].x, k0.x, s0); s0 = fmaf(q[k4+0].y, k0.y, s0);
        s0 = fmaf(q[k4+0].z, k0.z, s0); s0 = fmaf(q[k4+0].w, k0.w, s0);
        s1 = fmaf(q[k4+1].x, k1.x, s1); s1 = fmaf(q[k4+1].y, k1.y, s1);
        s1 = fmaf(q[k4+1].z, k1.z, s1); s1 = fmaf(q[k4+1].w, k1.w, s1);
        s2 = fmaf(q[k4+2].x, k2.x, s2); s2 = fmaf(q[k4+2].y, k2.y, s2);
        s2 = fmaf(q[k4+2].z, k2.z, s2); s2 = fmaf(q[k4+2].w, k2.w, s2);
        s3 = fmaf(q[k4+3].x, k3.x, s3); s3 = fmaf(q[k4+3].y, k3.y, s3);
        s3 = fmaf(q[k4+3].z, k3.z, s3); s3 = fmaf(q[k4+3].w, k3.w, s3);
      }
      const float scv = (s0 + s1) + (s2 + s3);
      const int tg = kt * 64 + t;
      sc[t2] = ((tg <= s) && (scv != 0.f)) ? scv : -INFINITY;
    }
    // online softmax across the 4 g-lanes (same wave)
    float mloc = sc[0];
#pragma unroll
    for (int t2 = 1; t2 < 16; ++t2) mloc = fmaxf(mloc, sc[t2]);
    mloc = fmaxf(mloc, __shfl_xor(mloc, 1));
    mloc = fmaxf(mloc, __shfl_xor(mloc, 2));
    const float mnew = fmaxf(m, mloc);
    const float r = (mnew == -INFINITY) ? 0.f : __expf(m - mnew);
    float psum = 0.f;
#pragma unroll
    for (int t2 = 0; t2 < 16; ++t2) {
      const float p = (sc[t2] == -INFINITY) ? 0.f : __expf(sc[t2] - mnew);
      sc[t2] = p;
      psum += p;
    }
    psum += __shfl_xor(psum, 1);
    psum += __shfl_xor(psum, 2);
    l = l * r + psum;
    m = mnew;
#pragma unroll
    for (int i = 0; i < 16; ++i) acc[i] *= r;
    // publish P (rows private to this wave -> no barrier)
#pragma unroll
    for (int t2 = 0; t2 < 16; ++t2) Ps[tq][(g << 4) + t2] = sc[t2];
    // PV
#pragma unroll 4
    for (int t = 0; t < 64; ++t) {
      const float pv = Ps[tq][t];
      const float* vr = &Vs[t][g << 4];
      float4 v0 = *(const float4*)(vr + 0);
      float4 v1 = *(const float4*)(vr + 4);
      float4 v2 = *(const float4*)(vr + 8);
      float4 v3 = *(const float4*)(vr + 12);
      acc[0]  = fmaf(pv, v0.x, acc[0]);  acc[1]  = fmaf(pv, v0.y, acc[1]);
      acc[2]  = fmaf(pv, v0.z, acc[2]);  acc[3]  = fmaf(pv, v0.w, acc[3]);
      acc[4]  = fmaf(pv, v1.x, acc[4]);  acc[5]  = fmaf(pv, v1.y, acc[5]);
      acc[6]  = fmaf(pv, v1.z, acc[6]);  acc[7]  = fmaf(pv, v1.w, acc[7]);
      acc[8]  = fmaf(pv, v2.x, acc[8]);  acc[9]  = fmaf(pv, v2.y, acc[9]);
      acc[10] = fmaf(pv, v2.z, acc[10]); acc[11] = fmaf(pv, v2.w, acc[11]);
      acc[12] = fmaf(pv, v3.x, acc[12]); acc[13] = fmaf(pv, v3.y, acc[13]);
      acc[14] = fmaf(pv, v3.z, acc[14]); acc[15] = fmaf(pv, v3.w, acc[15]);
    }
  }
  const float inv = 1.f / l;
  float* op = PVd + (((size_t)b * S + s) * H + h) * D + (g << 4);
#pragma unroll
  for (int i = 0; i < 4; ++i) {
    float4 o = make_float4(acc[i*4+0]*inv, acc[i*4+1]*inv, acc[i*4+2]*inv, acc[i*4+3]*inv);
    *(float4*)(op + i * 4) = o;
  }
}

// ---------------------------------------------------------------------------
// out[B*S, E] = PVd[B*S, H*D] @ W2[H*D, E] — same tiling as proj
// ---------------------------------------------------------------------------
__global__ __launch_bounds__(256) void out_kernel(
    const float* __restrict__ A, const float* __restrict__ W2,
    float* __restrict__ out) {
  const int rb = blockIdx.x;
  const int col0 = blockIdx.y * 64;
  __shared__ float As[64][68];
  __shared__ float Bs[64][68];
  const int tid = threadIdx.x;
  const int tx = tid & 15, ty = tid >> 4;
  const int row0 = rb * 64;
  constexpr int Kd = H * D;  // 512

  float acc[4][4] = {};
  for (int k0 = 0; k0 < Kd; k0 += 64) {
    __syncthreads();
#pragma unroll
    for (int j = 0; j < 4; ++j) {
      const int flat = tid + j * 256;
      const int r = flat >> 4, c4 = flat & 15;
      *(float4*)&As[r][c4 * 4] =
          *(const float4*)(A + (size_t)(row0 + r) * Kd + k0 + c4 * 4);
      *(float4*)&Bs[r][c4 * 4] =
          *(const float4*)(W2 + (size_t)(k0 + r) * E + col0 + c4 * 4);
    }
    __syncthreads();
#pragma unroll 8
    for (int k = 0; k < 64; ++k) {
      float a0 = As[ty * 4 + 0][k], a1 = As[ty * 4 + 1][k];
      float a2 = As[ty * 4 + 2][k], a3 = As[ty * 4 + 3][k];
      float4 bv = *(const float4*)&Bs[k][tx * 4];
      acc[0][0] = fmaf(a0, bv.x, acc[0][0]); acc[0][1] = fmaf(a0, bv.y, acc[0][1]);
      acc[0][2] = fmaf(a0, bv.z, acc[0][2]); acc[0][3] = fmaf(a0, bv.w, acc[0][3]);
      acc[1][0] = fmaf(a1, bv.x, acc[1][0]); acc[1][1] = fmaf(a1, bv.y, acc[1][1]);
      acc[1][2] = fmaf(a1, bv.z, acc[1][2]); acc[1][3] = fmaf(a1, bv.w, acc[1][3]);
      acc[2][0] = fmaf(a2, bv.x, acc[2][0]); acc[2][1] = fmaf(a2, bv.y, acc[2][1]);
      acc[2][2] = fmaf(a2, bv.z, acc[2][2]); acc[2][3] = fmaf(a2, bv.w, acc[2][3]);
      acc[3][0] = fmaf(a3, bv.x, acc[3][0]); acc[3][1] = fmaf(a3, bv.y, acc[3][1]);
      acc[3][2] = fmaf(a3, bv.z, acc[3][2]); acc[3][3] = fmaf(a3, bv.w, acc[3][3]);
    }
  }
#pragma unroll
  for (int i = 0; i < 4; ++i) {
    float4 v = make_float4(acc[i][0], acc[i][1], acc[i][2], acc[i][3]);
    *(float4*)(out + (size_t)(row0 + ty * 4 + i) * E + col0 + tx * 4) = v;
  }
}

}  // namespace

extern "C" void kernel_launch(void* const* d_in, const int* in_sizes, int n_in,
                              void* d_out, int out_size, void* d_ws, size_t ws_size,
                              hipStream_t stream) {
  const float* x   = (const float*)d_in[0];
  const float* Wq  = (const float*)d_in[1];
  const float* Wk  = (const float*)d_in[2];
  const float* Wvd = (const float*)d_in[3];
  const float* Wvu = (const float*)d_in[4];
  const float* Wo  = (const float*)d_in[5];
  float* out = (float*)d_out;

  const size_t nqk = (size_t)B * H * S * D;
  float* Q   = (float*)d_ws;
  float* K   = Q + nqk;
  float* Vd  = K + nqk;
  float* PVd = Vd + nqk;
  float* W2  = PVd + nqk;

  proj_kernel<<<dim3(B * S / 64, 24), 256, 0, stream>>>(x, Wq, Wk, Wvd, Q, K, Vd);
  w2_kernel<<<dim3(H * D * E / 256), 256, 0, stream>>>(Wvu, Wo, W2);
  attn_kernel<<<dim3(B * H, S / 64), 256, 0, stream>>>(Q, K, Vd, PVd);
  out_kernel<<<dim3(B * S / 64, E / 64), 256, 0, stream>>>(PVd, W2, out);
}

// Round 3
// 329.190 us; speedup vs baseline: 9.0867x; 2.2103x over previous
//
#include <hip/hip_runtime.h>
#include <math.h>

namespace {
constexpr int B = 4, S = 2048, E = 512, D = 64, H = 8;

typedef short bf8 __attribute__((ext_vector_type(8)));   // 8 bf16 raw bits
typedef short bf4 __attribute__((ext_vector_type(4)));   // 4 bf16 raw bits
typedef float f4 __attribute__((ext_vector_type(4)));

__device__ __forceinline__ short f2bf(float f) {
  union { float f; unsigned u; } v; v.f = f;
  const unsigned r = v.u + 0x7fffu + ((v.u >> 16) & 1u);  // RNE
  return (short)(r >> 16);
}

// ---------------------------------------------------------------------------
// proj: x[S,E] @ W[E,D] per (b,h,w) -> Q/K/Vd in bf16, layout [bh][S][D]
// ---------------------------------------------------------------------------
__global__ __launch_bounds__(256) void proj_kernel(
    const float* __restrict__ x, const float* __restrict__ Wq,
    const float* __restrict__ Wk, const float* __restrict__ Wvd,
    short* __restrict__ Q, short* __restrict__ K, short* __restrict__ Vd) {
  const int rb = blockIdx.x;
  const int cb = blockIdx.y;            // 0..23 -> (w, h)
  const int w = cb >> 3, h = cb & 7;
  const float* Wsel = (w == 0) ? Wq : (w == 1) ? Wk : Wvd;
  const float* Wp = Wsel + (size_t)h * E * D;
  short* Out = (w == 0) ? Q : (w == 1) ? K : Vd;

  __shared__ float As[64][68];
  __shared__ float Bs[64][68];
  const int tid = threadIdx.x;
  const int tx = tid & 15, ty = tid >> 4;
  const int row0 = rb * 64;

  float acc[4][4] = {};
  for (int k0 = 0; k0 < E; k0 += 64) {
    __syncthreads();
#pragma unroll
    for (int j = 0; j < 4; ++j) {
      const int flat = tid + j * 256;
      const int r = flat >> 4, c4 = flat & 15;
      *(float4*)&As[r][c4 * 4] =
          *(const float4*)(x + (size_t)(row0 + r) * E + k0 + c4 * 4);
      *(float4*)&Bs[r][c4 * 4] =
          *(const float4*)(Wp + (size_t)(k0 + r) * D + c4 * 4);
    }
    __syncthreads();
#pragma unroll 8
    for (int k = 0; k < 64; ++k) {
      float a0 = As[ty * 4 + 0][k], a1 = As[ty * 4 + 1][k];
      float a2 = As[ty * 4 + 2][k], a3 = As[ty * 4 + 3][k];
      float4 bv = *(const float4*)&Bs[k][tx * 4];
      acc[0][0] = fmaf(a0, bv.x, acc[0][0]); acc[0][1] = fmaf(a0, bv.y, acc[0][1]);
      acc[0][2] = fmaf(a0, bv.z, acc[0][2]); acc[0][3] = fmaf(a0, bv.w, acc[0][3]);
      acc[1][0] = fmaf(a1, bv.x, acc[1][0]); acc[1][1] = fmaf(a1, bv.y, acc[1][1]);
      acc[1][2] = fmaf(a1, bv.z, acc[1][2]); acc[1][3] = fmaf(a1, bv.w, acc[1][3]);
      acc[2][0] = fmaf(a2, bv.x, acc[2][0]); acc[2][1] = fmaf(a2, bv.y, acc[2][1]);
      acc[2][2] = fmaf(a2, bv.z, acc[2][2]); acc[2][3] = fmaf(a2, bv.w, acc[2][3]);
      acc[3][0] = fmaf(a3, bv.x, acc[3][0]); acc[3][1] = fmaf(a3, bv.y, acc[3][1]);
      acc[3][2] = fmaf(a3, bv.z, acc[3][2]); acc[3][3] = fmaf(a3, bv.w, acc[3][3]);
    }
  }
#pragma unroll
  for (int i = 0; i < 4; ++i) {
    const int row = row0 + ty * 4 + i;
    const int b = row >> 11, s = row & (S - 1);
    bf4 o;
    o[0] = f2bf(acc[i][0]); o[1] = f2bf(acc[i][1]);
    o[2] = f2bf(acc[i][2]); o[3] = f2bf(acc[i][3]);
    *(bf4*)(Out + (((size_t)(b * H + h) * S + s) * D) + tx * 4) = o;
  }
}

// W2[(h*D+d), e] = Wvu[h,d,e] * Wo[h]
__global__ __launch_bounds__(256) void w2_kernel(
    const float* __restrict__ Wvu, const float* __restrict__ Wo,
    float* __restrict__ W2) {
  const int idx = blockIdx.x * 256 + threadIdx.x;
  const int h = idx >> 15;
  W2[idx] = Wvu[idx] * Wo[h];
}

// ---------------------------------------------------------------------------
// attn: bf16 MFMA flash attention. Block = (bh, 64 q rows), 4 waves x 16 rows.
// K in LDS (XOR-swizzled 16B granules), V transposed in LDS, P via wave-private
// swizzled LDS. fp32 softmax. Masking: (t<=q) && (score != 0) else -inf.
// ---------------------------------------------------------------------------
__global__ __launch_bounds__(256) void attn_kernel(
    const short* __restrict__ Qb, const short* __restrict__ Kb,
    const short* __restrict__ Vb, float* __restrict__ PVd) {
  const int bh = blockIdx.x, qt = blockIdx.y;
  const int b = bh >> 3, h = bh & 7;
  const int tid = threadIdx.x;
  const int w = tid >> 6, l = tid & 63;
  const int lr = l & 15, hi = l >> 4;

  __shared__ short Ks[64 * 64];      // K[t][d], swizzled
  __shared__ short Vt[64 * 64];      // V^T[e][t], swizzled
  __shared__ short Ps[4][16 * 64];   // per-wave P[m][t], swizzled

  // Q fragments (A operand): row m=lr, k = half*32 + hi*8 + j
  const short* Qg = Qb + ((size_t)bh * S + qt * 64 + w * 16 + lr) * D;
  const bf8 qf0 = *(const bf8*)(Qg + hi * 8);
  const bf8 qf1 = *(const bf8*)(Qg + 32 + hi * 8);

  const short* Kg = Kb + (size_t)bh * S * D;
  const short* Vg = Vb + (size_t)bh * S * D;

  float mreg[4] = {-INFINITY, -INFINITY, -INFINITY, -INFINITY};
  float lsum[4] = {};
  f4 accO[4] = {};  // per e-tile, rows m = hi*4+reg

  for (int kt = 0; kt <= qt; ++kt) {
    __syncthreads();
    // stage K rows (coalesced b128 global -> swizzled b128 LDS)
#pragma unroll
    for (int i = 0; i < 2; ++i) {
      const int c = tid + i * 256;
      const int r = c >> 3, d8 = c & 7;
      *(bf8*)&Ks[r * 64 + ((d8 ^ (r & 7)) << 3)] =
          *(const bf8*)(Kg + (size_t)(kt * 64 + r) * D + d8 * 8);
    }
    // stage V transposed: Vt[e][t]
#pragma unroll
    for (int i = 0; i < 2; ++i) {
      const int t = tid & 63, e8 = (tid >> 6) + i * 4;
      const bf8 vv = *(const bf8*)(Vg + (size_t)(kt * 64 + t) * D + e8 * 8);
#pragma unroll
      for (int j = 0; j < 8; ++j) {
        const int e = e8 * 8 + j;
        Vt[e * 64 + (((t >> 3) ^ (e & 7)) << 3) + (t & 7)] = vv[j];
      }
    }
    __syncthreads();

    // QK^T: S[m=q][n=t], 4 n-tiles x 2 k-halves
    f4 accS[4] = {};
#pragma unroll
    for (int n = 0; n < 4; ++n) {
      const int tr = n * 16 + lr;
      const bf8 k0 = *(const bf8*)&Ks[tr * 64 + ((hi ^ (tr & 7)) << 3)];
      const bf8 k1 = *(const bf8*)&Ks[tr * 64 + (((4 + hi) ^ (tr & 7)) << 3)];
      accS[n] = __builtin_amdgcn_mfma_f32_16x16x32_bf16(qf0, k0, accS[n], 0, 0, 0);
      accS[n] = __builtin_amdgcn_mfma_f32_16x16x32_bf16(qf1, k1, accS[n], 0, 0, 0);
    }

    // scale + mask (reference-exact zero-set)
    float sc[4][4];
    const int q0 = qt * 64 + w * 16 + hi * 4;
#pragma unroll
    for (int n = 0; n < 4; ++n) {
      const int tg = kt * 64 + n * 16 + lr;
#pragma unroll
      for (int reg = 0; reg < 4; ++reg) {
        const float sv = accS[n][reg] * 0.125f;
        sc[n][reg] = ((tg <= q0 + reg) && (sv != 0.f)) ? sv : -INFINITY;
      }
    }

    // online softmax per q-row (row = reg, replicated over 16 t-lanes)
    float rn[4];
#pragma unroll
    for (int reg = 0; reg < 4; ++reg) {
      float v = fmaxf(fmaxf(sc[0][reg], sc[1][reg]), fmaxf(sc[2][reg], sc[3][reg]));
      v = fmaxf(v, __shfl_xor(v, 1));
      v = fmaxf(v, __shfl_xor(v, 2));
      v = fmaxf(v, __shfl_xor(v, 4));
      v = fmaxf(v, __shfl_xor(v, 8));
      const float mnew = fmaxf(mreg[reg], v);
      const float r = (mnew == -INFINITY) ? 0.f : __expf(mreg[reg] - mnew);
      float ps = 0.f;
#pragma unroll
      for (int n = 0; n < 4; ++n) {
        const float p = (sc[n][reg] == -INFINITY) ? 0.f : __expf(sc[n][reg] - mnew);
        sc[n][reg] = p;
        ps += p;
      }
      ps += __shfl_xor(ps, 1);
      ps += __shfl_xor(ps, 2);
      ps += __shfl_xor(ps, 4);
      ps += __shfl_xor(ps, 8);
      lsum[reg] = lsum[reg] * r + ps;
      mreg[reg] = mnew;
      rn[reg] = r;
    }
#pragma unroll
    for (int n = 0; n < 4; ++n)
#pragma unroll
      for (int reg = 0; reg < 4; ++reg) accO[n][reg] *= rn[reg];

    // publish P (bf16) to wave-private swizzled LDS
    short* Pw = Ps[w];
#pragma unroll
    for (int n = 0; n < 4; ++n) {
      const int g = 2 * n + (lr >> 3);
#pragma unroll
      for (int reg = 0; reg < 4; ++reg) {
        const int m = hi * 4 + reg;
        Pw[m * 64 + ((g ^ (m & 7)) << 3) + (lr & 7)] = f2bf(sc[n][reg]);
      }
    }

    // PV: O[m=q][n=e] += P[m][t] * Vt[e][t]
#pragma unroll
    for (int half = 0; half < 2; ++half) {
      const bf8 pf = *(const bf8*)&Pw[lr * 64 + (((half * 4 + hi) ^ (lr & 7)) << 3)];
#pragma unroll
      for (int n = 0; n < 4; ++n) {
        const int er = n * 16 + lr;
        const bf8 vf = *(const bf8*)&Vt[er * 64 + (((half * 4 + hi) ^ (er & 7)) << 3)];
        accO[n] = __builtin_amdgcn_mfma_f32_16x16x32_bf16(pf, vf, accO[n], 0, 0, 0);
      }
    }
  }

  // epilogue: normalize, write PVd [B,S,H*D] fp32
#pragma unroll
  for (int reg = 0; reg < 4; ++reg) {
    const float inv = 1.f / lsum[reg];
    const int s = qt * 64 + w * 16 + hi * 4 + reg;
    float* op = PVd + (size_t)(b * S + s) * (H * D) + h * D;
#pragma unroll
    for (int n = 0; n < 4; ++n) op[n * 16 + lr] = accO[n][reg] * inv;
  }
}

// ---------------------------------------------------------------------------
// out[B*S, E] = PVd[B*S, H*D] @ W2[H*D, E]
// ---------------------------------------------------------------------------
__global__ __launch_bounds__(256) void out_kernel(
    const float* __restrict__ A, const float* __restrict__ W2,
    float* __restrict__ out) {
  const int rb = blockIdx.x;
  const int col0 = blockIdx.y * 64;
  __shared__ float As[64][68];
  __shared__ float Bs[64][68];
  const int tid = threadIdx.x;
  const int tx = tid & 15, ty = tid >> 4;
  const int row0 = rb * 64;
  constexpr int Kd = H * D;

  float acc[4][4] = {};
  for (int k0 = 0; k0 < Kd; k0 += 64) {
    __syncthreads();
#pragma unroll
    for (int j = 0; j < 4; ++j) {
      const int flat = tid + j * 256;
      const int r = flat >> 4, c4 = flat & 15;
      *(float4*)&As[r][c4 * 4] =
          *(const float4*)(A + (size_t)(row0 + r) * Kd + k0 + c4 * 4);
      *(float4*)&Bs[r][c4 * 4] =
          *(const float4*)(W2 + (size_t)(k0 + r) * E + col0 + c4 * 4);
    }
    __syncthreads();
#pragma unroll 8
    for (int k = 0; k < 64; ++k) {
      float a0 = As[ty * 4 + 0][k], a1 = As[ty * 4 + 1][k];
      float a2 = As[ty * 4 + 2][k], a3 = As[ty * 4 + 3][k];
      float4 bv = *(const float4*)&Bs[k][tx * 4];
      acc[0][0] = fmaf(a0, bv.x, acc[0][0]); acc[0][1] = fmaf(a0, bv.y, acc[0][1]);
      acc[0][2] = fmaf(a0, bv.z, acc[0][2]); acc[0][3] = fmaf(a0, bv.w, acc[0][3]);
      acc[1][0] = fmaf(a1, bv.x, acc[1][0]); acc[1][1] = fmaf(a1, bv.y, acc[1][1]);
      acc[1][2] = fmaf(a1, bv.z, acc[1][2]); acc[1][3] = fmaf(a1, bv.w, acc[1][3]);
      acc[2][0] = fmaf(a2, bv.x, acc[2][0]); acc[2][1] = fmaf(a2, bv.y, acc[2][1]);
      acc[2][2] = fmaf(a2, bv.z, acc[2][2]); acc[2][3] = fmaf(a2, bv.w, acc[2][3]);
      acc[3][0] = fmaf(a3, bv.x, acc[3][0]); acc[3][1] = fmaf(a3, bv.y, acc[3][1]);
      acc[3][2] = fmaf(a3, bv.z, acc[3][2]); acc[3][3] = fmaf(a3, bv.w, acc[3][3]);
    }
  }
#pragma unroll
  for (int i = 0; i < 4; ++i) {
    float4 v = make_float4(acc[i][0], acc[i][1], acc[i][2], acc[i][3]);
    *(float4*)(out + (size_t)(row0 + ty * 4 + i) * E + col0 + tx * 4) = v;
  }
}

}  // namespace

extern "C" void kernel_launch(void* const* d_in, const int* in_sizes, int n_in,
                              void* d_out, int out_size, void* d_ws, size_t ws_size,
                              hipStream_t stream) {
  const float* x   = (const float*)d_in[0];
  const float* Wq  = (const float*)d_in[1];
  const float* Wk  = (const float*)d_in[2];
  const float* Wvd = (const float*)d_in[3];
  const float* Wvu = (const float*)d_in[4];
  const float* Wo  = (const float*)d_in[5];
  float* out = (float*)d_out;

  const size_t nqk = (size_t)B * H * S * D;  // 4.19M
  short* Qb = (short*)d_ws;
  short* Kb = Qb + nqk;
  short* Vb = Kb + nqk;
  float* PVd = (float*)(Vb + nqk);
  float* W2  = PVd + nqk;

  proj_kernel<<<dim3(B * S / 64, 24), 256, 0, stream>>>(x, Wq, Wk, Wvd, Qb, Kb, Vb);
  w2_kernel<<<dim3(H * D * E / 256), 256, 0, stream>>>(Wvu, Wo, W2);
  attn_kernel<<<dim3(B * H, S / 64), 256, 0, stream>>>(Qb, Kb, Vb, PVd);
  out_kernel<<<dim3(B * S / 64, E / 64), 256, 0, stream>>>(PVd, W2, out);
}

// Round 4
// 145.008 us; speedup vs baseline: 20.6283x; 2.2702x over previous
//
#include <hip/hip_runtime.h>
#include <math.h>

namespace {
constexpr int B = 4, S = 2048, E = 512, D = 64, H = 8;
constexpr int KD = 512;  // contraction dim of both big GEMMs

typedef short bf8 __attribute__((ext_vector_type(8)));
typedef short bf4 __attribute__((ext_vector_type(4)));
typedef float f4 __attribute__((ext_vector_type(4)));

__device__ __forceinline__ short f2bf(float f) {
  union { float f; unsigned u; } v; v.f = f;
  const unsigned r = v.u + 0x7fffu + ((v.u >> 16) & 1u);  // RNE
  return (short)(r >> 16);
}

__device__ __forceinline__ void gload16(const void* g, void* l) {
  __builtin_amdgcn_global_load_lds(
      (const __attribute__((address_space(1))) unsigned int*)g,
      (__attribute__((address_space(3))) unsigned int*)l, 16, 0, 0);
}

// ---------------------------------------------------------------------------
// x (fp32) -> xb (bf16), 8 elements/thread
// ---------------------------------------------------------------------------
__global__ __launch_bounds__(256) void xb_kernel(const float* __restrict__ x,
                                                 short* __restrict__ xb) {
  const size_t i = ((size_t)blockIdx.x * 256 + threadIdx.x) * 8;
  const float4 v0 = *(const float4*)(x + i);
  const float4 v1 = *(const float4*)(x + i + 4);
  bf8 o;
  o[0] = f2bf(v0.x); o[1] = f2bf(v0.y); o[2] = f2bf(v0.z); o[3] = f2bf(v0.w);
  o[4] = f2bf(v1.x); o[5] = f2bf(v1.y); o[6] = f2bf(v1.z); o[7] = f2bf(v1.w);
  *(bf8*)(xb + i) = o;
}

// ---------------------------------------------------------------------------
// WcatT[cb*64+d][e] = Wsel(w)[h][e][d]   (K-major weight concat, bf16)
// block = (cb, e0/64); 64x64 LDS transpose
// ---------------------------------------------------------------------------
__global__ __launch_bounds__(256) void wcat_kernel(
    const float* __restrict__ Wq, const float* __restrict__ Wk,
    const float* __restrict__ Wvd, short* __restrict__ WcatT) {
  const int cb = blockIdx.x;          // 0..23
  const int e0 = blockIdx.y * 64;
  const int w = cb >> 3, h = cb & 7;
  const float* Wsel = (w == 0) ? Wq : (w == 1) ? Wk : Wvd;
  const float* Wp = Wsel + (size_t)h * E * D;
  __shared__ float T[64][65];  // T[e][d]
  const int tid = threadIdx.x;
#pragma unroll
  for (int i = 0; i < 4; ++i) {
    const int f = tid + i * 256;
    const int r = f >> 4, c4 = f & 15;
    const float4 v = *(const float4*)(Wp + (size_t)(e0 + r) * D + c4 * 4);
    T[r][c4 * 4 + 0] = v.x; T[r][c4 * 4 + 1] = v.y;
    T[r][c4 * 4 + 2] = v.z; T[r][c4 * 4 + 3] = v.w;
  }
  __syncthreads();
#pragma unroll
  for (int i = 0; i < 4; ++i) {
    const int f = tid + i * 256;
    const int dr = f >> 4, e4 = f & 15;
    bf4 o;
#pragma unroll
    for (int j = 0; j < 4; ++j) o[j] = f2bf(T[e4 * 4 + j][dr]);
    *(bf4*)(WcatT + (size_t)(cb * 64 + dr) * KD + e0 + e4 * 4) = o;
  }
}

// ---------------------------------------------------------------------------
// W2T[e][h*64+d] = Wvu[h][d][e] * Wo[h]   (K-major, bf16)
// block = (h, e0/64)
// ---------------------------------------------------------------------------
__global__ __launch_bounds__(256) void w2t_kernel(
    const float* __restrict__ Wvu, const float* __restrict__ Wo,
    short* __restrict__ W2T) {
  const int h = blockIdx.x;
  const int e0 = blockIdx.y * 64;
  const float wo = Wo[h];
  __shared__ float T[64][65];  // T[d][e]
  const int tid = threadIdx.x;
#pragma unroll
  for (int i = 0; i < 4; ++i) {
    const int f = tid + i * 256;
    const int r = f >> 4, c4 = f & 15;
    const float4 v = *(const float4*)(Wvu + ((size_t)h * D + r) * E + e0 + c4 * 4);
    T[r][c4 * 4 + 0] = v.x * wo; T[r][c4 * 4 + 1] = v.y * wo;
    T[r][c4 * 4 + 2] = v.z * wo; T[r][c4 * 4 + 3] = v.w * wo;
  }
  __syncthreads();
#pragma unroll
  for (int i = 0; i < 4; ++i) {
    const int f = tid + i * 256;
    const int er = f >> 4, d4 = f & 15;
    bf4 o;
#pragma unroll
    for (int j = 0; j < 4; ++j) o[j] = f2bf(T[d4 * 4 + j][er]);
    *(bf4*)(W2T + (size_t)(e0 + er) * KD + h * 64 + d4 * 4) = o;
  }
}

// ---------------------------------------------------------------------------
// bf16 MFMA GEMM: C[M,N] = A[M,512] @ Bt[N,512]^T.  128x128 tile, BK=64,
// 4 waves each 64x64. LDS staged via global_load_lds (linear dest,
// inverse-swizzled source; reads apply the same XOR -> conflict-free).
// MODE 0: proj epilogue (scatter bf16 into Q/K/Vd [bh][S][D])
// MODE 1: out epilogue (fp32, row-major [M,512])
// ---------------------------------------------------------------------------
template <int MODE>
__global__ __launch_bounds__(256) void gemm_kernel(
    const short* __restrict__ A, const short* __restrict__ Bt,
    short* __restrict__ Qb, short* __restrict__ Kb, short* __restrict__ Vb,
    float* __restrict__ Of) {
  const int row0 = blockIdx.x * 128;
  const int ct = blockIdx.y;
  const int tid = threadIdx.x;
  const int w = tid >> 6, l = tid & 63;
  const int wm = w >> 1, wn = w & 1;
  const int lr = l & 15, hi = l >> 4;

  __shared__ short As[128 * 64];
  __shared__ short Bs[128 * 64];

  const short* Ag = A + (size_t)row0 * KD;
  const short* Bg = Bt + (size_t)ct * 128 * KD;

  f4 acc[4][4] = {};
  for (int k0 = 0; k0 < KD; k0 += 64) {
    __syncthreads();
#pragma unroll
    for (int i = 0; i < 4; ++i) {
      const int f = i * 256 + tid;
      const int r = f >> 3, g = f & 7;
      gload16(Ag + (size_t)r * KD + k0 + ((g ^ (r & 7)) << 3), &As[f * 8]);
    }
#pragma unroll
    for (int i = 0; i < 4; ++i) {
      const int f = i * 256 + tid;
      const int r = f >> 3, g = f & 7;
      gload16(Bg + (size_t)r * KD + k0 + ((g ^ (r & 7)) << 3), &Bs[f * 8]);
    }
    __syncthreads();

    bf8 af[4][2], bf[4][2];
#pragma unroll
    for (int t = 0; t < 4; ++t) {
#pragma unroll
      for (int kh = 0; kh < 2; ++kh) {
        const int ar = wm * 64 + t * 16 + lr;
        af[t][kh] = *(const bf8*)&As[ar * 64 + (((kh * 4 + hi) ^ (ar & 7)) << 3)];
        const int br = wn * 64 + t * 16 + lr;
        bf[t][kh] = *(const bf8*)&Bs[br * 64 + (((kh * 4 + hi) ^ (br & 7)) << 3)];
      }
    }
#pragma unroll
    for (int mt = 0; mt < 4; ++mt)
#pragma unroll
      for (int nt = 0; nt < 4; ++nt) {
        acc[mt][nt] =
            __builtin_amdgcn_mfma_f32_16x16x32_bf16(af[mt][0], bf[nt][0], acc[mt][nt], 0, 0, 0);
        acc[mt][nt] =
            __builtin_amdgcn_mfma_f32_16x16x32_bf16(af[mt][1], bf[nt][1], acc[mt][nt], 0, 0, 0);
      }
  }

  if constexpr (MODE == 0) {
#pragma unroll
    for (int nt = 0; nt < 4; ++nt) {
      const int gc = ct * 128 + wn * 64 + nt * 16 + lr;
      const int cb = gc >> 6, d = gc & 63;
      short* Out = (cb < 8) ? Qb : (cb < 16) ? Kb : Vb;
      const int h = cb & 7;
#pragma unroll
      for (int mt = 0; mt < 4; ++mt)
#pragma unroll
        for (int reg = 0; reg < 4; ++reg) {
          const int grow = row0 + wm * 64 + mt * 16 + hi * 4 + reg;
          const int b = grow >> 11, s = grow & (S - 1);
          Out[(((size_t)(b * H + h) * S + s) << 6) + d] = f2bf(acc[mt][nt][reg]);
        }
    }
  } else {
#pragma unroll
    for (int mt = 0; mt < 4; ++mt)
#pragma unroll
      for (int reg = 0; reg < 4; ++reg) {
        const int grow = row0 + wm * 64 + mt * 16 + hi * 4 + reg;
        float* orow = Of + (size_t)grow * 512 + ct * 128 + wn * 64;
#pragma unroll
        for (int nt = 0; nt < 4; ++nt) orow[nt * 16 + lr] = acc[mt][nt][reg];
      }
  }
}

// ---------------------------------------------------------------------------
// attn: bf16 MFMA flash attention (unchanged except bf16 PVd epilogue)
// ---------------------------------------------------------------------------
__global__ __launch_bounds__(256) void attn_kernel(
    const short* __restrict__ Qb, const short* __restrict__ Kb,
    const short* __restrict__ Vb, short* __restrict__ PVb) {
  const int bh = blockIdx.x, qt = blockIdx.y;
  const int b = bh >> 3, h = bh & 7;
  const int tid = threadIdx.x;
  const int w = tid >> 6, l = tid & 63;
  const int lr = l & 15, hi = l >> 4;

  __shared__ short Ks[64 * 64];
  __shared__ short Vt[64 * 64];
  __shared__ short Ps[4][16 * 64];

  const short* Qg = Qb + ((size_t)bh * S + qt * 64 + w * 16 + lr) * D;
  const bf8 qf0 = *(const bf8*)(Qg + hi * 8);
  const bf8 qf1 = *(const bf8*)(Qg + 32 + hi * 8);

  const short* Kg = Kb + (size_t)bh * S * D;
  const short* Vg = Vb + (size_t)bh * S * D;

  float mreg[4] = {-INFINITY, -INFINITY, -INFINITY, -INFINITY};
  float lsum[4] = {};
  f4 accO[4] = {};

  for (int kt = 0; kt <= qt; ++kt) {
    __syncthreads();
#pragma unroll
    for (int i = 0; i < 2; ++i) {
      const int c = tid + i * 256;
      const int r = c >> 3, d8 = c & 7;
      *(bf8*)&Ks[r * 64 + ((d8 ^ (r & 7)) << 3)] =
          *(const bf8*)(Kg + (size_t)(kt * 64 + r) * D + d8 * 8);
    }
#pragma unroll
    for (int i = 0; i < 2; ++i) {
      const int t = tid & 63, e8 = (tid >> 6) + i * 4;
      const bf8 vv = *(const bf8*)(Vg + (size_t)(kt * 64 + t) * D + e8 * 8);
#pragma unroll
      for (int j = 0; j < 8; ++j) {
        const int e = e8 * 8 + j;
        Vt[e * 64 + (((t >> 3) ^ (e & 7)) << 3) + (t & 7)] = vv[j];
      }
    }
    __syncthreads();

    f4 accS[4] = {};
#pragma unroll
    for (int n = 0; n < 4; ++n) {
      const int tr = n * 16 + lr;
      const bf8 k0 = *(const bf8*)&Ks[tr * 64 + ((hi ^ (tr & 7)) << 3)];
      const bf8 k1 = *(const bf8*)&Ks[tr * 64 + (((4 + hi) ^ (tr & 7)) << 3)];
      accS[n] = __builtin_amdgcn_mfma_f32_16x16x32_bf16(qf0, k0, accS[n], 0, 0, 0);
      accS[n] = __builtin_amdgcn_mfma_f32_16x16x32_bf16(qf1, k1, accS[n], 0, 0, 0);
    }

    float sc[4][4];
    const int q0 = qt * 64 + w * 16 + hi * 4;
#pragma unroll
    for (int n = 0; n < 4; ++n) {
      const int tg = kt * 64 + n * 16 + lr;
#pragma unroll
      for (int reg = 0; reg < 4; ++reg) {
        const float sv = accS[n][reg] * 0.125f;
        sc[n][reg] = ((tg <= q0 + reg) && (sv != 0.f)) ? sv : -INFINITY;
      }
    }

    float rn[4];
#pragma unroll
    for (int reg = 0; reg < 4; ++reg) {
      float v = fmaxf(fmaxf(sc[0][reg], sc[1][reg]), fmaxf(sc[2][reg], sc[3][reg]));
      v = fmaxf(v, __shfl_xor(v, 1));
      v = fmaxf(v, __shfl_xor(v, 2));
      v = fmaxf(v, __shfl_xor(v, 4));
      v = fmaxf(v, __shfl_xor(v, 8));
      const float mnew = fmaxf(mreg[reg], v);
      const float r = (mnew == -INFINITY) ? 0.f : __expf(mreg[reg] - mnew);
      float ps = 0.f;
#pragma unroll
      for (int n = 0; n < 4; ++n) {
        const float p = (sc[n][reg] == -INFINITY) ? 0.f : __expf(sc[n][reg] - mnew);
        sc[n][reg] = p;
        ps += p;
      }
      ps += __shfl_xor(ps, 1);
      ps += __shfl_xor(ps, 2);
      ps += __shfl_xor(ps, 4);
      ps += __shfl_xor(ps, 8);
      lsum[reg] = lsum[reg] * r + ps;
      mreg[reg] = mnew;
      rn[reg] = r;
    }
#pragma unroll
    for (int n = 0; n < 4; ++n)
#pragma unroll
      for (int reg = 0; reg < 4; ++reg) accO[n][reg] *= rn[reg];

    short* Pw = Ps[w];
#pragma unroll
    for (int n = 0; n < 4; ++n) {
      const int g = 2 * n + (lr >> 3);
#pragma unroll
      for (int reg = 0; reg < 4; ++reg) {
        const int m = hi * 4 + reg;
        Pw[m * 64 + ((g ^ (m & 7)) << 3) + (lr & 7)] = f2bf(sc[n][reg]);
      }
    }

#pragma unroll
    for (int half = 0; half < 2; ++half) {
      const bf8 pf = *(const bf8*)&Pw[lr * 64 + (((half * 4 + hi) ^ (lr & 7)) << 3)];
#pragma unroll
      for (int n = 0; n < 4; ++n) {
        const int er = n * 16 + lr;
        const bf8 vf = *(const bf8*)&Vt[er * 64 + (((half * 4 + hi) ^ (er & 7)) << 3)];
        accO[n] = __builtin_amdgcn_mfma_f32_16x16x32_bf16(pf, vf, accO[n], 0, 0, 0);
      }
    }
  }

  // epilogue: normalize, write PVd [B,S,H*D] in bf16
#pragma unroll
  for (int reg = 0; reg < 4; ++reg) {
    const float inv = 1.f / lsum[reg];
    const int s = qt * 64 + w * 16 + hi * 4 + reg;
    short* op = PVb + (size_t)(b * S + s) * (H * D) + h * D;
#pragma unroll
    for (int n = 0; n < 4; ++n) op[n * 16 + lr] = f2bf(accO[n][reg] * inv);
  }
}

}  // namespace

extern "C" void kernel_launch(void* const* d_in, const int* in_sizes, int n_in,
                              void* d_out, int out_size, void* d_ws, size_t ws_size,
                              hipStream_t stream) {
  const float* x   = (const float*)d_in[0];
  const float* Wq  = (const float*)d_in[1];
  const float* Wk  = (const float*)d_in[2];
  const float* Wvd = (const float*)d_in[3];
  const float* Wvu = (const float*)d_in[4];
  const float* Wo  = (const float*)d_in[5];
  float* out = (float*)d_out;

  const size_t nqk = (size_t)B * H * S * D;  // 4.19M
  short* xb    = (short*)d_ws;
  short* Qb    = xb + nqk;
  short* Kb    = Qb + nqk;
  short* Vb    = Kb + nqk;
  short* PVb   = Vb + nqk;
  short* WcatT = PVb + nqk;            // [1536][512]
  short* W2T   = WcatT + 1536 * KD;    // [512][512]

  xb_kernel<<<dim3(B * S * E / (256 * 8)), 256, 0, stream>>>(x, xb);
  wcat_kernel<<<dim3(24, 8), 256, 0, stream>>>(Wq, Wk, Wvd, WcatT);
  w2t_kernel<<<dim3(8, 8), 256, 0, stream>>>(Wvu, Wo, W2T);
  gemm_kernel<0><<<dim3(64, 12), 256, 0, stream>>>(xb, WcatT, Qb, Kb, Vb, nullptr);
  attn_kernel<<<dim3(B * H, S / 64), 256, 0, stream>>>(Qb, Kb, Vb, PVb);
  gemm_kernel<1><<<dim3(64, 4), 256, 0, stream>>>(PVb, W2T, nullptr, nullptr, nullptr, out);
}

// Round 5
// 125.210 us; speedup vs baseline: 23.8900x; 1.1581x over previous
//
#include <hip/hip_runtime.h>
#include <math.h>

namespace {
constexpr int B = 4, S = 2048, E = 512, D = 64, H = 8;
constexpr int KD = 512;

typedef short bf8 __attribute__((ext_vector_type(8)));
typedef short bf4 __attribute__((ext_vector_type(4)));
typedef float f4 __attribute__((ext_vector_type(4)));

__device__ __forceinline__ short f2bf(float f) {
  union { float f; unsigned u; } v; v.f = f;
  const unsigned r = v.u + 0x7fffu + ((v.u >> 16) & 1u);  // RNE
  return (short)(r >> 16);
}

__device__ __forceinline__ void gload16(const void* g, void* l) {
  __builtin_amdgcn_global_load_lds(
      (const __attribute__((address_space(1))) unsigned int*)g,
      (__attribute__((address_space(3))) unsigned int*)l, 16, 0, 0);
}

// ---------------------------------------------------------------------------
// x (fp32) -> xb (bf16)
// ---------------------------------------------------------------------------
__global__ __launch_bounds__(256) void xb_kernel(const float* __restrict__ x,
                                                 short* __restrict__ xb) {
  const size_t i = ((size_t)blockIdx.x * 256 + threadIdx.x) * 8;
  const float4 v0 = *(const float4*)(x + i);
  const float4 v1 = *(const float4*)(x + i + 4);
  bf8 o;
  o[0] = f2bf(v0.x); o[1] = f2bf(v0.y); o[2] = f2bf(v0.z); o[3] = f2bf(v0.w);
  o[4] = f2bf(v1.x); o[5] = f2bf(v1.y); o[6] = f2bf(v1.z); o[7] = f2bf(v1.w);
  *(bf8*)(xb + i) = o;
}

// ---------------------------------------------------------------------------
// WcatT[cb*64+d][e] = Wsel(w)[h][e][d]   (K-major weight concat, bf16)
// ---------------------------------------------------------------------------
__global__ __launch_bounds__(256) void wcat_kernel(
    const float* __restrict__ Wq, const float* __restrict__ Wk,
    const float* __restrict__ Wvd, short* __restrict__ WcatT) {
  const int cb = blockIdx.x;
  const int e0 = blockIdx.y * 64;
  const int w = cb >> 3, h = cb & 7;
  const float* Wsel = (w == 0) ? Wq : (w == 1) ? Wk : Wvd;
  const float* Wp = Wsel + (size_t)h * E * D;
  __shared__ float T[64][65];
  const int tid = threadIdx.x;
#pragma unroll
  for (int i = 0; i < 4; ++i) {
    const int f = tid + i * 256;
    const int r = f >> 4, c4 = f & 15;
    const float4 v = *(const float4*)(Wp + (size_t)(e0 + r) * D + c4 * 4);
    T[r][c4 * 4 + 0] = v.x; T[r][c4 * 4 + 1] = v.y;
    T[r][c4 * 4 + 2] = v.z; T[r][c4 * 4 + 3] = v.w;
  }
  __syncthreads();
#pragma unroll
  for (int i = 0; i < 4; ++i) {
    const int f = tid + i * 256;
    const int dr = f >> 4, e4 = f & 15;
    bf4 o;
#pragma unroll
    for (int j = 0; j < 4; ++j) o[j] = f2bf(T[e4 * 4 + j][dr]);
    *(bf4*)(WcatT + (size_t)(cb * 64 + dr) * KD + e0 + e4 * 4) = o;
  }
}

// ---------------------------------------------------------------------------
// W2T[e][h*64+d] = Wvu[h][d][e] * Wo[h]   (K-major, bf16)
// ---------------------------------------------------------------------------
__global__ __launch_bounds__(256) void w2t_kernel(
    const float* __restrict__ Wvu, const float* __restrict__ Wo,
    short* __restrict__ W2T) {
  const int h = blockIdx.x;
  const int e0 = blockIdx.y * 64;
  const float wo = Wo[h];
  __shared__ float T[64][65];
  const int tid = threadIdx.x;
#pragma unroll
  for (int i = 0; i < 4; ++i) {
    const int f = tid + i * 256;
    const int r = f >> 4, c4 = f & 15;
    const float4 v = *(const float4*)(Wvu + ((size_t)h * D + r) * E + e0 + c4 * 4);
    T[r][c4 * 4 + 0] = v.x * wo; T[r][c4 * 4 + 1] = v.y * wo;
    T[r][c4 * 4 + 2] = v.z * wo; T[r][c4 * 4 + 3] = v.w * wo;
  }
  __syncthreads();
#pragma unroll
  for (int i = 0; i < 4; ++i) {
    const int f = tid + i * 256;
    const int er = f >> 4, d4 = f & 15;
    bf4 o;
#pragma unroll
    for (int j = 0; j < 4; ++j) o[j] = f2bf(T[d4 * 4 + j][er]);
    *(bf4*)(W2T + (size_t)(e0 + er) * KD + h * 64 + d4 * 4) = o;
  }
}

// ---------------------------------------------------------------------------
// Vb[bh][t][e] -> Vt[bh][e][t]  (64x64 LDS tile transpose)
// ---------------------------------------------------------------------------
__global__ __launch_bounds__(256) void vt_kernel(const short* __restrict__ Vb,
                                                 short* __restrict__ Vt) {
  const int bh = blockIdx.x, tt = blockIdx.y;
  __shared__ short T[64][72];
  const int tid = threadIdx.x;
#pragma unroll
  for (int i = 0; i < 2; ++i) {
    const int f = i * 256 + tid;
    const int t = f >> 3, g = f & 7;
    *(bf8*)&T[t][g * 8] =
        *(const bf8*)(Vb + ((size_t)bh * S + tt * 64 + t) * D + g * 8);
  }
  __syncthreads();
#pragma unroll
  for (int i = 0; i < 2; ++i) {
    const int f = i * 256 + tid;
    const int e = f >> 3, t0 = (f & 7) * 8;
    bf8 o;
#pragma unroll
    for (int j = 0; j < 8; ++j) o[j] = T[t0 + j][e];
    *(bf8*)(Vt + ((size_t)bh * D + e) * S + tt * 64 + t0) = o;
  }
}

// ---------------------------------------------------------------------------
// bf16 MFMA GEMM (unchanged from round 4)
// ---------------------------------------------------------------------------
template <int MODE>
__global__ __launch_bounds__(256) void gemm_kernel(
    const short* __restrict__ A, const short* __restrict__ Bt,
    short* __restrict__ Qb, short* __restrict__ Kb, short* __restrict__ Vb,
    float* __restrict__ Of) {
  const int row0 = blockIdx.x * 128;
  const int ct = blockIdx.y;
  const int tid = threadIdx.x;
  const int w = tid >> 6, l = tid & 63;
  const int wm = w >> 1, wn = w & 1;
  const int lr = l & 15, hi = l >> 4;

  __shared__ short As[128 * 64];
  __shared__ short Bs[128 * 64];

  const short* Ag = A + (size_t)row0 * KD;
  const short* Bg = Bt + (size_t)ct * 128 * KD;

  f4 acc[4][4] = {};
  for (int k0 = 0; k0 < KD; k0 += 64) {
    __syncthreads();
#pragma unroll
    for (int i = 0; i < 4; ++i) {
      const int f = i * 256 + tid;
      const int r = f >> 3, g = f & 7;
      gload16(Ag + (size_t)r * KD + k0 + ((g ^ (r & 7)) << 3), &As[f * 8]);
    }
#pragma unroll
    for (int i = 0; i < 4; ++i) {
      const int f = i * 256 + tid;
      const int r = f >> 3, g = f & 7;
      gload16(Bg + (size_t)r * KD + k0 + ((g ^ (r & 7)) << 3), &Bs[f * 8]);
    }
    __syncthreads();

    bf8 af[4][2], bf[4][2];
#pragma unroll
    for (int t = 0; t < 4; ++t) {
#pragma unroll
      for (int kh = 0; kh < 2; ++kh) {
        const int ar = wm * 64 + t * 16 + lr;
        af[t][kh] = *(const bf8*)&As[ar * 64 + (((kh * 4 + hi) ^ (ar & 7)) << 3)];
        const int br = wn * 64 + t * 16 + lr;
        bf[t][kh] = *(const bf8*)&Bs[br * 64 + (((kh * 4 + hi) ^ (br & 7)) << 3)];
      }
    }
#pragma unroll
    for (int mt = 0; mt < 4; ++mt)
#pragma unroll
      for (int nt = 0; nt < 4; ++nt) {
        acc[mt][nt] =
            __builtin_amdgcn_mfma_f32_16x16x32_bf16(af[mt][0], bf[nt][0], acc[mt][nt], 0, 0, 0);
        acc[mt][nt] =
            __builtin_amdgcn_mfma_f32_16x16x32_bf16(af[mt][1], bf[nt][1], acc[mt][nt], 0, 0, 0);
      }
  }

  if constexpr (MODE == 0) {
#pragma unroll
    for (int nt = 0; nt < 4; ++nt) {
      const int gc = ct * 128 + wn * 64 + nt * 16 + lr;
      const int cb = gc >> 6, d = gc & 63;
      short* Out = (cb < 8) ? Qb : (cb < 16) ? Kb : Vb;
      const int h = cb & 7;
#pragma unroll
      for (int mt = 0; mt < 4; ++mt)
#pragma unroll
        for (int reg = 0; reg < 4; ++reg) {
          const int grow = row0 + wm * 64 + mt * 16 + hi * 4 + reg;
          const int b = grow >> 11, s = grow & (S - 1);
          Out[(((size_t)(b * H + h) * S + s) << 6) + d] = f2bf(acc[mt][nt][reg]);
        }
    }
  } else {
#pragma unroll
    for (int mt = 0; mt < 4; ++mt)
#pragma unroll
      for (int reg = 0; reg < 4; ++reg) {
        const int grow = row0 + wm * 64 + mt * 16 + hi * 4 + reg;
        float* orow = Of + (size_t)grow * 512 + ct * 128 + wn * 64;
#pragma unroll
        for (int nt = 0; nt < 4; ++nt) orow[nt * 16 + lr] = acc[mt][nt][reg];
      }
  }
}

// ---------------------------------------------------------------------------
// attn v2: double-buffered gload_lds staging, one barrier/iter, V^T input.
// Block (bh, qt) with qt inverted for longest-first dispatch.
// ---------------------------------------------------------------------------
__global__ __launch_bounds__(256) void attn_kernel(
    const short* __restrict__ Qb, const short* __restrict__ Kb,
    const short* __restrict__ Vt, short* __restrict__ PVb) {
  const int bh = blockIdx.x;
  const int qt = (int)(gridDim.y - 1 - blockIdx.y);  // longest-first
  const int b = bh >> 3, h = bh & 7;
  const int tid = threadIdx.x;
  const int w = tid >> 6, l = tid & 63;
  const int lr = l & 15, hi = l >> 4;

  __shared__ short Ks[2][64 * 64];
  __shared__ short Vs[2][64 * 64];
  __shared__ short Ps[4][16 * 64];

  const short* Qg = Qb + ((size_t)bh * S + qt * 64 + w * 16 + lr) * D;
  const bf8 qf0 = *(const bf8*)(Qg + hi * 8);
  const bf8 qf1 = *(const bf8*)(Qg + 32 + hi * 8);

  const short* Kg = Kb + (size_t)bh * S * D;   // [t][64]
  const short* Vg = Vt + (size_t)bh * D * S;   // [e][S]

  const int sr = tid >> 3, sg = tid & 7;       // staging row/granule (f = tid)
  const int sswz = (sg ^ (sr & 7)) << 3;

  float mreg[4] = {-INFINITY, -INFINITY, -INFINITY, -INFINITY};
  float lsum[4] = {};
  f4 accO[4] = {};

  // prologue: stage tile 0 into buf 0
  {
    const int r2 = sr + 32, swz2 = (sg ^ (r2 & 7)) << 3;
    gload16(Kg + (size_t)sr * D + sswz, &Ks[0][tid * 8]);
    gload16(Kg + (size_t)r2 * D + swz2, &Ks[0][(256 + tid) * 8]);
    gload16(Vg + (size_t)sr * S + sswz, &Vs[0][tid * 8]);
    gload16(Vg + (size_t)r2 * S + swz2, &Vs[0][(256 + tid) * 8]);
  }
  __syncthreads();

  int buf = 0;
  for (int kt = 0; kt <= qt; ++kt) {
    // issue prefetch of next tile (latency hidden under compute below)
    if (kt < qt) {
      const int nb = buf ^ 1;
      const size_t koff = (size_t)(kt + 1) * 64;
      const int r2 = sr + 32, swz2 = (sg ^ (r2 & 7)) << 3;
      gload16(Kg + (koff + sr) * D + sswz, &Ks[nb][tid * 8]);
      gload16(Kg + (koff + r2) * D + swz2, &Ks[nb][(256 + tid) * 8]);
      gload16(Vg + (size_t)sr * S + koff + sswz, &Vs[nb][tid * 8]);
      gload16(Vg + (size_t)r2 * S + koff + swz2, &Vs[nb][(256 + tid) * 8]);
    }

    // QK^T
    f4 accS[4] = {};
    __builtin_amdgcn_s_setprio(1);
#pragma unroll
    for (int n = 0; n < 4; ++n) {
      const int tr = n * 16 + lr;
      const bf8 k0 = *(const bf8*)&Ks[buf][tr * 64 + ((hi ^ (tr & 7)) << 3)];
      const bf8 k1 = *(const bf8*)&Ks[buf][tr * 64 + (((4 + hi) ^ (tr & 7)) << 3)];
      accS[n] = __builtin_amdgcn_mfma_f32_16x16x32_bf16(qf0, k0, accS[n], 0, 0, 0);
      accS[n] = __builtin_amdgcn_mfma_f32_16x16x32_bf16(qf1, k1, accS[n], 0, 0, 0);
    }
    __builtin_amdgcn_s_setprio(0);

    // scale + mask (reference-exact zero-set)
    float sc[4][4];
    const int q0 = qt * 64 + w * 16 + hi * 4;
#pragma unroll
    for (int n = 0; n < 4; ++n) {
      const int tg = kt * 64 + n * 16 + lr;
#pragma unroll
      for (int reg = 0; reg < 4; ++reg) {
        const float sv = accS[n][reg] * 0.125f;
        sc[n][reg] = ((tg <= q0 + reg) && (sv != 0.f)) ? sv : -INFINITY;
      }
    }

    // online softmax per q-row
    float rn[4];
#pragma unroll
    for (int reg = 0; reg < 4; ++reg) {
      float v = fmaxf(fmaxf(sc[0][reg], sc[1][reg]), fmaxf(sc[2][reg], sc[3][reg]));
      v = fmaxf(v, __shfl_xor(v, 1));
      v = fmaxf(v, __shfl_xor(v, 2));
      v = fmaxf(v, __shfl_xor(v, 4));
      v = fmaxf(v, __shfl_xor(v, 8));
      const float mnew = fmaxf(mreg[reg], v);
      const float r = __expf(mreg[reg] - mnew);  // mreg=-inf -> 0
      float ps = 0.f;
#pragma unroll
      for (int n = 0; n < 4; ++n) {
        const float p = __expf(sc[n][reg] - mnew);  // sc=-inf -> 0
        sc[n][reg] = p;
        ps += p;
      }
      ps += __shfl_xor(ps, 1);
      ps += __shfl_xor(ps, 2);
      ps += __shfl_xor(ps, 4);
      ps += __shfl_xor(ps, 8);
      lsum[reg] = lsum[reg] * r + ps;
      mreg[reg] = mnew;
      rn[reg] = r;
    }
#pragma unroll
    for (int n = 0; n < 4; ++n)
#pragma unroll
      for (int reg = 0; reg < 4; ++reg) accO[n][reg] *= rn[reg];

    // publish P (bf16) to wave-private swizzled LDS
    short* Pw = Ps[w];
#pragma unroll
    for (int n = 0; n < 4; ++n) {
      const int g = 2 * n + (lr >> 3);
#pragma unroll
      for (int reg = 0; reg < 4; ++reg) {
        const int m = hi * 4 + reg;
        Pw[m * 64 + ((g ^ (m & 7)) << 3) + (lr & 7)] = f2bf(sc[n][reg]);
      }
    }

    // PV
    __builtin_amdgcn_s_setprio(1);
#pragma unroll
    for (int kh = 0; kh < 2; ++kh) {
      const bf8 pf = *(const bf8*)&Pw[lr * 64 + (((kh * 4 + hi) ^ (lr & 7)) << 3)];
#pragma unroll
      for (int n = 0; n < 4; ++n) {
        const int er = n * 16 + lr;
        const bf8 vf = *(const bf8*)&Vs[buf][er * 64 + (((kh * 4 + hi) ^ (er & 7)) << 3)];
        accO[n] = __builtin_amdgcn_mfma_f32_16x16x32_bf16(pf, vf, accO[n], 0, 0, 0);
      }
    }
    __builtin_amdgcn_s_setprio(0);

    __syncthreads();  // drains vmcnt(0): prefetch complete; all waves synced
    buf ^= 1;
  }

  // epilogue
#pragma unroll
  for (int reg = 0; reg < 4; ++reg) {
    const float inv = 1.f / lsum[reg];
    const int s = qt * 64 + w * 16 + hi * 4 + reg;
    short* op = PVb + (size_t)(b * S + s) * (H * D) + h * D;
#pragma unroll
    for (int n = 0; n < 4; ++n) op[n * 16 + lr] = f2bf(accO[n][reg] * inv);
  }
}

}  // namespace

extern "C" void kernel_launch(void* const* d_in, const int* in_sizes, int n_in,
                              void* d_out, int out_size, void* d_ws, size_t ws_size,
                              hipStream_t stream) {
  const float* x   = (const float*)d_in[0];
  const float* Wq  = (const float*)d_in[1];
  const float* Wk  = (const float*)d_in[2];
  const float* Wvd = (const float*)d_in[3];
  const float* Wvu = (const float*)d_in[4];
  const float* Wo  = (const float*)d_in[5];
  float* out = (float*)d_out;

  const size_t nqk = (size_t)B * H * S * D;  // 4.19M
  short* xb    = (short*)d_ws;
  short* Qb    = xb + nqk;
  short* Kb    = Qb + nqk;
  short* Vb    = Kb + nqk;
  short* Vtg   = Vb + nqk;
  short* PVb   = Vtg + nqk;
  short* WcatT = PVb + nqk;            // [1536][512]
  short* W2T   = WcatT + 1536 * KD;    // [512][512]

  xb_kernel<<<dim3(B * S * E / (256 * 8)), 256, 0, stream>>>(x, xb);
  wcat_kernel<<<dim3(24, 8), 256, 0, stream>>>(Wq, Wk, Wvd, WcatT);
  w2t_kernel<<<dim3(8, 8), 256, 0, stream>>>(Wvu, Wo, W2T);
  gemm_kernel<0><<<dim3(64, 12), 256, 0, stream>>>(xb, WcatT, Qb, Kb, Vb, nullptr);
  vt_kernel<<<dim3(B * H, S / 64), 256, 0, stream>>>(Vb, Vtg);
  attn_kernel<<<dim3(B * H, S / 64), 256, 0, stream>>>(Qb, Kb, Vtg, PVb);
  gemm_kernel<1><<<dim3(64, 4), 256, 0, stream>>>(PVb, W2T, nullptr, nullptr, nullptr, out);
}